// Round 4
// baseline (106.043 us; speedup 1.0000x reference)
//
#include <hip/hip_runtime.h>

#define NB 2
#define SQL 256
#define NH 16
#define HD 64
#define EMB 1024

// log2(e) / sqrt(EMBED): folded into Wq so softmax = 2^(q*k)
__device__ __constant__ float kQSCALE = 1.4426950408889634f / 32.0f;

__device__ __forceinline__ float fexp2(float x) { return __builtin_amdgcn_exp2f(x); }
__device__ __forceinline__ float frcp(float x)  { return __builtin_amdgcn_rcpf(x); }

__device__ __forceinline__ float4 pexp2(float4 q, float4 k) {
    return make_float4(fexp2(q.x * k.x), fexp2(q.y * k.y),
                       fexp2(q.z * k.z), fexp2(q.w * k.w));
}
__device__ __forceinline__ void paccum(float4& a, float4 p, float rs, float4 v) {
    a.x = fmaf(p.x * rs, v.x, a.x);
    a.y = fmaf(p.y * rs, v.y, a.y);
    a.z = fmaf(p.z * rs, v.z, a.z);
    a.w = fmaf(p.w * rs, v.w, a.w);
}

// ---------------------------------------------------------------------------
// Kernel 1: q/k/v projections. TWO blocks per (n,s): each computes 32 of the
// 64 e-outputs. Output layout [ns][e*16+h]. Wq pre-scaled by kQSCALE.
// ---------------------------------------------------------------------------
__global__ __launch_bounds__(256) void qkv_kernel(
    const float* __restrict__ x,
    const float* __restrict__ Wq,
    const float* __restrict__ Wk,
    const float* __restrict__ Wv,
    float* __restrict__ Q,
    float* __restrict__ K,
    float* __restrict__ V)
{
    __shared__ float wq[32 * 68];
    __shared__ float wk[32 * 68];
    __shared__ float wv[32 * 68];
    __shared__ float xs[16 * 68];

    const int tid  = threadIdx.x;
    const int ns   = blockIdx.x >> 1;
    const int half = blockIdx.x & 1;

    {
        const int h  = tid >> 4;
        const int d0 = (tid & 15) * 4;
        const float4 a = ((const float4*)(x + (size_t)ns * EMB))[tid];
        *(float4*)&xs[h * 68 + d0] = a;
    }
#pragma unroll
    for (int j = 0; j < 2; ++j) {
        const int f4 = j * 256 + tid;
        const int e  = f4 >> 4;
        const int d4 = f4 & 15;
        const int g  = half * 512 + f4;
        float4 a = ((const float4*)Wq)[g];
        a.x *= kQSCALE; a.y *= kQSCALE; a.z *= kQSCALE; a.w *= kQSCALE;
        *(float4*)&wq[e * 68 + d4 * 4] = a;
        *(float4*)&wk[e * 68 + d4 * 4] = ((const float4*)Wk)[g];
        *(float4*)&wv[e * 68 + d4 * 4] = ((const float4*)Wv)[g];
    }
    __syncthreads();

    const int el = tid >> 3;
    const int h0 = (tid & 7) * 2;

    float aq[2] = {0.f, 0.f}, ak[2] = {0.f, 0.f}, av[2] = {0.f, 0.f};

#pragma unroll
    for (int d4 = 0; d4 < 16; ++d4) {
        const float4 wqv = *(const float4*)&wq[el * 68 + d4 * 4];
        const float4 wkv = *(const float4*)&wk[el * 68 + d4 * 4];
        const float4 wvv = *(const float4*)&wv[el * 68 + d4 * 4];
#pragma unroll
        for (int hh = 0; hh < 2; ++hh) {
            const float4 xv = *(const float4*)&xs[(h0 + hh) * 68 + d4 * 4];
            aq[hh] = fmaf(xv.x, wqv.x, fmaf(xv.y, wqv.y, fmaf(xv.z, wqv.z, fmaf(xv.w, wqv.w, aq[hh]))));
            ak[hh] = fmaf(xv.x, wkv.x, fmaf(xv.y, wkv.y, fmaf(xv.z, wkv.z, fmaf(xv.w, wkv.w, ak[hh]))));
            av[hh] = fmaf(xv.x, wvv.x, fmaf(xv.y, wvv.y, fmaf(xv.z, wvv.z, fmaf(xv.w, wvv.w, av[hh]))));
        }
    }
    const size_t off = (size_t)ns * EMB + half * 512 + 2 * tid;
    *(float2*)&Q[off] = make_float2(aq[0], aq[1]);
    *(float2*)&K[off] = make_float2(ak[0], ak[1]);
    *(float2*)&V[off] = make_float2(av[0], av[1]);
}

// ---------------------------------------------------------------------------
// Kernel 2: fused elementwise-energy -> softmax over h (16) -> sum over t.
// COALESCED lane map: lane l loads float4 at linear offset 4l + 256j of each
// 1024-float row (1 KB contiguous per instruction). Lane l holds h-quad
// (l&3) of e = 16j + (l>>2); h-sum = 3 local adds + 2 quad-perm shfl_xor.
// Wave = 2 s-values; block = 8 s x 16-wide t-chunk; grid 1024.
// ---------------------------------------------------------------------------
__global__ __attribute__((amdgpu_waves_per_eu(4, 4))) __launch_bounds__(256)
void attn_kernel(
    const float* __restrict__ Q,
    const float* __restrict__ K,
    const float* __restrict__ V,
    float* __restrict__ AO)
{
    const int b    = blockIdx.x;
    const int tc   = b & 15;
    const int st   = (b >> 4) & 31;
    const int n    = b >> 9;
    const int wave = threadIdx.x >> 6;
    const int l    = threadIdx.x & 63;
    const int s0   = st * 8 + wave * 2;

    float4 q0[4], q1[4], a0[4], a1[4];
    {
        const float4* qp0 = (const float4*)(Q + (size_t)(n * SQL + s0) * EMB) + l;
        const float4* qp1 = qp0 + 256;   // next s row
#pragma unroll
        for (int j = 0; j < 4; ++j) { q0[j] = qp0[j * 64]; q1[j] = qp1[j * 64]; }
    }
#pragma unroll
    for (int j = 0; j < 4; ++j) {
        a0[j] = make_float4(0.f, 0.f, 0.f, 0.f);
        a1[j] = make_float4(0.f, 0.f, 0.f, 0.f);
    }

    const int t0 = tc * 16;
    const float4* kp = (const float4*)(K + (size_t)(n * SQL + t0) * EMB) + l;
    const float4* vp = (const float4*)(V + (size_t)(n * SQL + t0) * EMB) + l;

    for (int tt = 0; tt < 16; ++tt) {
        const float4 k0 = kp[0], k1 = kp[64], k2 = kp[128], k3 = kp[192];
        const float4 v0 = vp[0], v1 = vp[64], v2 = vp[128], v3 = vp[192];
        kp += 256; vp += 256;
        // ---- s0 stream ----
        {
            float4 p0 = pexp2(q0[0], k0), p1 = pexp2(q0[1], k1);
            float4 p2 = pexp2(q0[2], k2), p3 = pexp2(q0[3], k3);
            float u0 = (p0.x + p0.y) + (p0.z + p0.w);
            float u1 = (p1.x + p1.y) + (p1.z + p1.w);
            float u2 = (p2.x + p2.y) + (p2.z + p2.w);
            float u3 = (p3.x + p3.y) + (p3.z + p3.w);
            u0 += __shfl_xor(u0, 1); u0 += __shfl_xor(u0, 2);
            u1 += __shfl_xor(u1, 1); u1 += __shfl_xor(u1, 2);
            u2 += __shfl_xor(u2, 1); u2 += __shfl_xor(u2, 2);
            u3 += __shfl_xor(u3, 1); u3 += __shfl_xor(u3, 2);
            paccum(a0[0], p0, frcp(u0), v0);
            paccum(a0[1], p1, frcp(u1), v1);
            paccum(a0[2], p2, frcp(u2), v2);
            paccum(a0[3], p3, frcp(u3), v3);
        }
        __builtin_amdgcn_sched_barrier(0);
        // ---- s1 stream ----
        {
            float4 p0 = pexp2(q1[0], k0), p1 = pexp2(q1[1], k1);
            float4 p2 = pexp2(q1[2], k2), p3 = pexp2(q1[3], k3);
            float u0 = (p0.x + p0.y) + (p0.z + p0.w);
            float u1 = (p1.x + p1.y) + (p1.z + p1.w);
            float u2 = (p2.x + p2.y) + (p2.z + p2.w);
            float u3 = (p3.x + p3.y) + (p3.z + p3.w);
            u0 += __shfl_xor(u0, 1); u0 += __shfl_xor(u0, 2);
            u1 += __shfl_xor(u1, 1); u1 += __shfl_xor(u1, 2);
            u2 += __shfl_xor(u2, 1); u2 += __shfl_xor(u2, 2);
            u3 += __shfl_xor(u3, 1); u3 += __shfl_xor(u3, 2);
            paccum(a1[0], p0, frcp(u0), v0);
            paccum(a1[1], p1, frcp(u1), v1);
            paccum(a1[2], p2, frcp(u2), v2);
            paccum(a1[3], p3, frcp(u3), v3);
        }
    }

    // lane l holds (e = 16j + (l>>2), h = 4(l&3)+c): AO index = h*64 + e
    float* aoB0 = AO + (size_t)(n * SQL + s0) * EMB + 256 * (l & 3) + (l >> 2);
    float* aoB1 = aoB0 + EMB;
#pragma unroll
    for (int j = 0; j < 4; ++j) {
        atomicAdd(aoB0 + 16 * j +   0, a0[j].x);
        atomicAdd(aoB0 + 16 * j +  64, a0[j].y);
        atomicAdd(aoB0 + 16 * j + 128, a0[j].z);
        atomicAdd(aoB0 + 16 * j + 192, a0[j].w);
        atomicAdd(aoB1 + 16 * j +   0, a1[j].x);
        atomicAdd(aoB1 + 16 * j +  64, a1[j].y);
        atomicAdd(aoB1 + 16 * j + 128, a1[j].z);
        atomicAdd(aoB1 + 16 * j + 192, a1[j].w);
    }
}

// ---------------------------------------------------------------------------
// Kernel 3: out = AO @ Wo^T (f32 vector GEMM). 64r x 32j tile, k-split 4.
// Grid = 8rt * 32jt * 4kc = 1024 blocks. Deterministic partials P[kc].
// ---------------------------------------------------------------------------
__global__ __launch_bounds__(256) void proj_kernel(
    const float* __restrict__ A,
    const float* __restrict__ Wo,
    float* __restrict__ P)
{
    __shared__ float As[32][68];
    __shared__ float Ws[32][36];

    const int b  = blockIdx.x;
    const int kc = b & 3;
    const int jt = (b >> 2) & 31;
    const int rt = b >> 7;
    const int tid = threadIdx.x;
    const int tx = tid & 15;
    const int ty = tid >> 4;
    const int r0 = rt * 64, j0 = jt * 32, k0 = kc * 256;

    float2 c2[4];
#pragma unroll
    for (int i = 0; i < 4; ++i) c2[i] = make_float2(0.f, 0.f);

    for (int kt = 0; kt < 8; ++kt) {
        const int kb = k0 + kt * 32;
        __syncthreads();
#pragma unroll
        for (int it = 0; it < 2; ++it) {
            const int f   = it * 256 + tid;
            const int row = f >> 3;
            const int kq  = f & 7;
            const float4 a = *(const float4*)&A[(size_t)(r0 + row) * EMB + kb + kq * 4];
            As[kq * 4 + 0][row] = a.x;
            As[kq * 4 + 1][row] = a.y;
            As[kq * 4 + 2][row] = a.z;
            As[kq * 4 + 3][row] = a.w;
        }
        {
            const int row = tid >> 3;
            const int kq  = tid & 7;
            const float4 w = *(const float4*)&Wo[(size_t)(j0 + row) * EMB + kb + kq * 4];
            Ws[kq * 4 + 0][row] = w.x;
            Ws[kq * 4 + 1][row] = w.y;
            Ws[kq * 4 + 2][row] = w.z;
            Ws[kq * 4 + 3][row] = w.w;
        }
        __syncthreads();
#pragma unroll
        for (int kk = 0; kk < 32; ++kk) {
            const float4 a4 = *(const float4*)&As[kk][ty * 4];
            const float2 w2 = *(const float2*)&Ws[kk][tx * 2];
            c2[0].x = fmaf(a4.x, w2.x, c2[0].x); c2[0].y = fmaf(a4.x, w2.y, c2[0].y);
            c2[1].x = fmaf(a4.y, w2.x, c2[1].x); c2[1].y = fmaf(a4.y, w2.y, c2[1].y);
            c2[2].x = fmaf(a4.z, w2.x, c2[2].x); c2[2].y = fmaf(a4.z, w2.y, c2[2].y);
            c2[3].x = fmaf(a4.w, w2.x, c2[3].x); c2[3].y = fmaf(a4.w, w2.y, c2[3].y);
        }
    }

    float* p = P + (size_t)kc * 524288;
#pragma unroll
    for (int rr = 0; rr < 4; ++rr) {
        *(float2*)&p[(size_t)(r0 + ty * 4 + rr) * EMB + j0 + tx * 2] = c2[rr];
    }
}

__global__ __launch_bounds__(256) void reduce_kernel(
    const float* __restrict__ P,
    const float* __restrict__ bo,
    float* __restrict__ out)
{
    const int f4 = blockIdx.x * 256 + threadIdx.x;   // 131072 float4s
    const float4* P4 = (const float4*)P;
    const float4 a = P4[f4];
    const float4 b = P4[131072 + f4];
    const float4 c = P4[262144 + f4];
    const float4 d = P4[393216 + f4];
    const float4 bb = ((const float4*)bo)[f4 & 255];
    float4 o;
    o.x = ((a.x + b.x) + (c.x + d.x)) + bb.x;
    o.y = ((a.y + b.y) + (c.y + d.y)) + bb.y;
    o.z = ((a.z + b.z) + (c.z + d.z)) + bb.z;
    o.w = ((a.w + b.w) + (c.w + d.w)) + bb.w;
    ((float4*)out)[f4] = o;
}

extern "C" void kernel_launch(void* const* d_in, const int* in_sizes, int n_in,
                              void* d_out, int out_size, void* d_ws, size_t ws_size,
                              hipStream_t stream)
{
    const float* x  = (const float*)d_in[0];
    const float* Wq = (const float*)d_in[1];
    const float* Wk = (const float*)d_in[2];
    const float* Wv = (const float*)d_in[3];
    const float* Wo = (const float*)d_in[4];
    const float* bo = (const float*)d_in[5];

    float* ws = (float*)d_ws;
    float* Q  = ws;                 // 524288 floats
    float* K  = ws + 524288;        // 524288
    float* V  = ws + 1048576;       // 524288
    float* AO = ws + 1572864;       // 524288
    float* P  = ws + 2097152;       // 4 * 524288

    hipMemsetAsync(AO, 0, 524288 * sizeof(float), stream);
    qkv_kernel<<<1024, 256, 0, stream>>>(x, Wq, Wk, Wv, Q, K, V);
    attn_kernel<<<1024, 256, 0, stream>>>(Q, K, V, AO);
    proj_kernel<<<1024, 256, 0, stream>>>(AO, Wo, P);
    reduce_kernel<<<512, 256, 0, stream>>>(P, bo, (float*)d_out);
}

// Round 5
// 84.588 us; speedup vs baseline: 1.2536x; 1.2536x over previous
//
#include <hip/hip_runtime.h>

#define NB 2
#define SQL 256
#define NH 16
#define HD 64
#define EMB 1024

typedef unsigned short ushortT;
typedef unsigned int uintT;

// log2(e) / sqrt(EMBED): folded into Wq so softmax = 2^(q*k)
__device__ __constant__ float kQSCALE = 1.4426950408889634f / 32.0f;

__device__ __forceinline__ float fexp2(float x) { return __builtin_amdgcn_exp2f(x); }
__device__ __forceinline__ float frcp(float x)  { return __builtin_amdgcn_rcpf(x); }

__device__ __forceinline__ ushortT f2bf(float x) {
    uintT u = __float_as_uint(x);
    u += 0x7fffu + ((u >> 16) & 1u);        // RNE
    return (ushortT)(u >> 16);
}
// unpack 8 bf16 (element order = memory order) to f32
__device__ __forceinline__ void unpk8(uint4 u, float* f) {
    f[0] = __uint_as_float(u.x << 16); f[1] = __uint_as_float(u.x & 0xffff0000u);
    f[2] = __uint_as_float(u.y << 16); f[3] = __uint_as_float(u.y & 0xffff0000u);
    f[4] = __uint_as_float(u.z << 16); f[5] = __uint_as_float(u.z & 0xffff0000u);
    f[6] = __uint_as_float(u.w << 16); f[7] = __uint_as_float(u.w & 0xffff0000u);
}

// ---------------------------------------------------------------------------
// Kernel 1: q/k/v projections -> bf16. TWO blocks per (n,s), each computing
// 32 of 64 e-outputs. Output element order [ns][e*16+h]. Wq pre-scaled.
// ---------------------------------------------------------------------------
__global__ __launch_bounds__(256) void qkv_kernel(
    const float* __restrict__ x,
    const float* __restrict__ Wq,
    const float* __restrict__ Wk,
    const float* __restrict__ Wv,
    ushortT* __restrict__ Q,
    ushortT* __restrict__ K,
    ushortT* __restrict__ V)
{
    __shared__ float wq[32 * 68];
    __shared__ float wk[32 * 68];
    __shared__ float wv[32 * 68];
    __shared__ float xs[16 * 68];

    const int tid  = threadIdx.x;
    const int ns   = blockIdx.x >> 1;
    const int half = blockIdx.x & 1;

    {
        const int h  = tid >> 4;
        const int d0 = (tid & 15) * 4;
        const float4 a = ((const float4*)(x + (size_t)ns * EMB))[tid];
        *(float4*)&xs[h * 68 + d0] = a;
    }
#pragma unroll
    for (int j = 0; j < 2; ++j) {
        const int f4 = j * 256 + tid;
        const int e  = f4 >> 4;
        const int d4 = f4 & 15;
        const int g  = half * 512 + f4;
        float4 a = ((const float4*)Wq)[g];
        a.x *= kQSCALE; a.y *= kQSCALE; a.z *= kQSCALE; a.w *= kQSCALE;
        *(float4*)&wq[e * 68 + d4 * 4] = a;
        *(float4*)&wk[e * 68 + d4 * 4] = ((const float4*)Wk)[g];
        *(float4*)&wv[e * 68 + d4 * 4] = ((const float4*)Wv)[g];
    }
    __syncthreads();

    const int el = tid >> 3;
    const int h0 = (tid & 7) * 2;

    float aq[2] = {0.f, 0.f}, ak[2] = {0.f, 0.f}, av[2] = {0.f, 0.f};

#pragma unroll
    for (int d4 = 0; d4 < 16; ++d4) {
        const float4 wqv = *(const float4*)&wq[el * 68 + d4 * 4];
        const float4 wkv = *(const float4*)&wk[el * 68 + d4 * 4];
        const float4 wvv = *(const float4*)&wv[el * 68 + d4 * 4];
#pragma unroll
        for (int hh = 0; hh < 2; ++hh) {
            const float4 xv = *(const float4*)&xs[(h0 + hh) * 68 + d4 * 4];
            aq[hh] = fmaf(xv.x, wqv.x, fmaf(xv.y, wqv.y, fmaf(xv.z, wqv.z, fmaf(xv.w, wqv.w, aq[hh]))));
            ak[hh] = fmaf(xv.x, wkv.x, fmaf(xv.y, wkv.y, fmaf(xv.z, wkv.z, fmaf(xv.w, wkv.w, ak[hh]))));
            av[hh] = fmaf(xv.x, wvv.x, fmaf(xv.y, wvv.y, fmaf(xv.z, wvv.z, fmaf(xv.w, wvv.w, av[hh]))));
        }
    }
    const size_t off = (size_t)ns * EMB + half * 512 + 2 * tid;   // even
    *(ushort2*)&Q[off] = make_ushort2(f2bf(aq[0]), f2bf(aq[1]));
    *(ushort2*)&K[off] = make_ushort2(f2bf(ak[0]), f2bf(ak[1]));
    *(ushort2*)&V[off] = make_ushort2(f2bf(av[0]), f2bf(av[1]));
}

// ---------------------------------------------------------------------------
// Kernel 2: fused energy -> softmax(h) -> sum(t). bf16 Q/K/V.
// Wave tile: 2 s-values x HALF the e-range (eh). Lane l holds 8 consecutive
// bf16 (one uint4): e = 32*eh + (l>>1), h-octet 8*(l&1)..+7. h-sum = 7 local
// adds + 1 shfl_xor(1). Registers fit ~60 VGPR -> no spill (round-4 lesson).
// Grid: 2n * 32st(8s) * 2eh * 16tc = 2048 blocks, 4 waves each.
// ---------------------------------------------------------------------------
__global__ __launch_bounds__(256) void attn_kernel(
    const ushortT* __restrict__ Q,
    const ushortT* __restrict__ K,
    const ushortT* __restrict__ V,
    float* __restrict__ AO)
{
    const int b    = blockIdx.x;
    const int tc   = b & 15;
    const int eh   = (b >> 4) & 1;
    const int st   = (b >> 5) & 31;
    const int n    = b >> 10;
    const int wave = threadIdx.x >> 6;
    const int l    = threadIdx.x & 63;
    const int s0   = st * 8 + wave * 2;
    const int t0   = tc * 16;

    const uint4* qp = (const uint4*)(Q + (size_t)(n * SQL + s0) * EMB + 512 * eh) + l;
    const uint4 q0pk = qp[0];
    const uint4 q1pk = qp[128];     // next s row = 1024 ushorts = 128 uint4

    float a0[8], a1[8];
#pragma unroll
    for (int i = 0; i < 8; ++i) { a0[i] = 0.f; a1[i] = 0.f; }

    const uint4* kp = (const uint4*)(K + (size_t)(n * SQL + t0) * EMB + 512 * eh) + l;
    const uint4* vp = (const uint4*)(V + (size_t)(n * SQL + t0) * EMB + 512 * eh) + l;

    for (int tt = 0; tt < 16; ++tt) {
        const uint4 kk = kp[0];
        const uint4 vv = vp[0];
        kp += 128; vp += 128;
        float ku[8], vu[8];
        unpk8(kk, ku);
        unpk8(vv, vu);
        // ---- s0 ----
        {
            float qa[8], p[8];
            unpk8(q0pk, qa);
#pragma unroll
            for (int i = 0; i < 8; ++i) p[i] = fexp2(qa[i] * ku[i]);
            float u = ((p[0] + p[1]) + (p[2] + p[3])) + ((p[4] + p[5]) + (p[6] + p[7]));
            u += __shfl_xor(u, 1);
            const float rs = frcp(u);
#pragma unroll
            for (int i = 0; i < 8; ++i) a0[i] = fmaf(p[i] * rs, vu[i], a0[i]);
        }
        __builtin_amdgcn_sched_barrier(0);   // cap liveness: don't co-schedule the two streams
        // ---- s1 ----
        {
            float qa[8], p[8];
            unpk8(q1pk, qa);
#pragma unroll
            for (int i = 0; i < 8; ++i) p[i] = fexp2(qa[i] * ku[i]);
            float u = ((p[0] + p[1]) + (p[2] + p[3])) + ((p[4] + p[5]) + (p[6] + p[7]));
            u += __shfl_xor(u, 1);
            const float rs = frcp(u);
#pragma unroll
            for (int i = 0; i < 8; ++i) a1[i] = fmaf(p[i] * rs, vu[i], a1[i]);
        }
    }

    // element (within row) = 512eh + 8l + c  ->  e = 32eh+(l>>1), h = 8(l&1)+c
    // AO channel = h*64 + e = 512(l&1) + 64c + 32eh + (l>>1)
    float* base0 = AO + (size_t)(n * SQL + s0) * EMB + 512 * (l & 1) + 32 * eh + (l >> 1);
    float* base1 = base0 + EMB;
#pragma unroll
    for (int c = 0; c < 8; ++c) {
        atomicAdd(base0 + 64 * c, a0[c]);
        atomicAdd(base1 + 64 * c, a1[c]);
    }
}

// ---------------------------------------------------------------------------
// Kernel 3: out = AO @ Wo^T (f32 vector GEMM). 64r x 32j tile, k-split 4.
// Grid = 8rt * 32jt * 4kc = 1024 blocks. Deterministic partials P[kc].
// ---------------------------------------------------------------------------
__global__ __launch_bounds__(256) void proj_kernel(
    const float* __restrict__ A,
    const float* __restrict__ Wo,
    float* __restrict__ P)
{
    __shared__ float As[32][68];
    __shared__ float Ws[32][36];

    const int b  = blockIdx.x;
    const int kc = b & 3;
    const int jt = (b >> 2) & 31;
    const int rt = b >> 7;
    const int tid = threadIdx.x;
    const int tx = tid & 15;
    const int ty = tid >> 4;
    const int r0 = rt * 64, j0 = jt * 32, k0 = kc * 256;

    float2 c2[4];
#pragma unroll
    for (int i = 0; i < 4; ++i) c2[i] = make_float2(0.f, 0.f);

    for (int kt = 0; kt < 8; ++kt) {
        const int kb = k0 + kt * 32;
        __syncthreads();
#pragma unroll
        for (int it = 0; it < 2; ++it) {
            const int f   = it * 256 + tid;
            const int row = f >> 3;
            const int kq  = f & 7;
            const float4 a = *(const float4*)&A[(size_t)(r0 + row) * EMB + kb + kq * 4];
            As[kq * 4 + 0][row] = a.x;
            As[kq * 4 + 1][row] = a.y;
            As[kq * 4 + 2][row] = a.z;
            As[kq * 4 + 3][row] = a.w;
        }
        {
            const int row = tid >> 3;
            const int kq  = tid & 7;
            const float4 w = *(const float4*)&Wo[(size_t)(j0 + row) * EMB + kb + kq * 4];
            Ws[kq * 4 + 0][row] = w.x;
            Ws[kq * 4 + 1][row] = w.y;
            Ws[kq * 4 + 2][row] = w.z;
            Ws[kq * 4 + 3][row] = w.w;
        }
        __syncthreads();
#pragma unroll
        for (int kk = 0; kk < 32; ++kk) {
            const float4 a4 = *(const float4*)&As[kk][ty * 4];
            const float2 w2 = *(const float2*)&Ws[kk][tx * 2];
            c2[0].x = fmaf(a4.x, w2.x, c2[0].x); c2[0].y = fmaf(a4.x, w2.y, c2[0].y);
            c2[1].x = fmaf(a4.y, w2.x, c2[1].x); c2[1].y = fmaf(a4.y, w2.y, c2[1].y);
            c2[2].x = fmaf(a4.z, w2.x, c2[2].x); c2[2].y = fmaf(a4.z, w2.y, c2[2].y);
            c2[3].x = fmaf(a4.w, w2.x, c2[3].x); c2[3].y = fmaf(a4.w, w2.y, c2[3].y);
        }
    }

    float* p = P + (size_t)kc * 524288;
#pragma unroll
    for (int rr = 0; rr < 4; ++rr) {
        *(float2*)&p[(size_t)(r0 + ty * 4 + rr) * EMB + j0 + tx * 2] = c2[rr];
    }
}

__global__ __launch_bounds__(256) void reduce_kernel(
    const float* __restrict__ P,
    const float* __restrict__ bo,
    float* __restrict__ out)
{
    const int f4 = blockIdx.x * 256 + threadIdx.x;   // 131072 float4s
    const float4* P4 = (const float4*)P;
    const float4 a = P4[f4];
    const float4 b = P4[131072 + f4];
    const float4 c = P4[262144 + f4];
    const float4 d = P4[393216 + f4];
    const float4 bb = ((const float4*)bo)[f4 & 255];
    float4 o;
    o.x = ((a.x + b.x) + (c.x + d.x)) + bb.x;
    o.y = ((a.y + b.y) + (c.y + d.y)) + bb.y;
    o.z = ((a.z + b.z) + (c.z + d.z)) + bb.z;
    o.w = ((a.w + b.w) + (c.w + d.w)) + bb.w;
    ((float4*)out)[f4] = o;
}

extern "C" void kernel_launch(void* const* d_in, const int* in_sizes, int n_in,
                              void* d_out, int out_size, void* d_ws, size_t ws_size,
                              hipStream_t stream)
{
    const float* x  = (const float*)d_in[0];
    const float* Wq = (const float*)d_in[1];
    const float* Wk = (const float*)d_in[2];
    const float* Wv = (const float*)d_in[3];
    const float* Wo = (const float*)d_in[4];
    const float* bo = (const float*)d_in[5];

    float* ws = (float*)d_ws;
    ushortT* Q = (ushortT*)ws;              // 524288 bf16 = 1 MB
    ushortT* K = (ushortT*)(ws + 262144);   // 1 MB
    ushortT* V = (ushortT*)(ws + 524288);   // 1 MB
    float* AO  = ws + 786432;               // 524288 f32 = 2 MB
    float* P   = ws + 1310720;              // 4 x 524288 f32 = 8 MB

    hipMemsetAsync(AO, 0, 524288 * sizeof(float), stream);
    qkv_kernel<<<1024, 256, 0, stream>>>(x, Wq, Wk, Wv, Q, K, V);
    attn_kernel<<<2048, 256, 0, stream>>>(Q, K, V, AO);
    proj_kernel<<<1024, 256, 0, stream>>>(AO, Wo, P);
    reduce_kernel<<<512, 256, 0, stream>>>(P, bo, (float*)d_out);
}

// Round 6
// 83.207 us; speedup vs baseline: 1.2745x; 1.0166x over previous
//
#include <hip/hip_runtime.h>

#define NB 2
#define SQL 256
#define NH 16
#define HD 64
#define EMB 1024

typedef unsigned short ushortT;
typedef unsigned int uintT;

// log2(e) / sqrt(EMBED): folded into Wq so softmax = 2^(q*k)
__device__ __constant__ float kQSCALE = 1.4426950408889634f / 32.0f;

__device__ __forceinline__ float fexp2(float x) { return __builtin_amdgcn_exp2f(x); }
__device__ __forceinline__ float frcp(float x)  { return __builtin_amdgcn_rcpf(x); }

__device__ __forceinline__ ushortT f2bf(float x) {
    uintT u = __float_as_uint(x);
    u += 0x7fffu + ((u >> 16) & 1u);        // RNE
    return (ushortT)(u >> 16);
}
// unpack 8 bf16 (element order = memory order) to f32
__device__ __forceinline__ void unpk8(uint4 u, float* f) {
    f[0] = __uint_as_float(u.x << 16); f[1] = __uint_as_float(u.x & 0xffff0000u);
    f[2] = __uint_as_float(u.y << 16); f[3] = __uint_as_float(u.y & 0xffff0000u);
    f[4] = __uint_as_float(u.z << 16); f[5] = __uint_as_float(u.z & 0xffff0000u);
    f[6] = __uint_as_float(u.w << 16); f[7] = __uint_as_float(u.w & 0xffff0000u);
}

// ---------------------------------------------------------------------------
// Kernel 1: q/k/v projections -> bf16. TWO blocks per (n,s), each computing
// 32 of 64 e-outputs. Output element order [ns][e*16+h]. Wq pre-scaled.
// ---------------------------------------------------------------------------
__global__ __launch_bounds__(256) void qkv_kernel(
    const float* __restrict__ x,
    const float* __restrict__ Wq,
    const float* __restrict__ Wk,
    const float* __restrict__ Wv,
    ushortT* __restrict__ Q,
    ushortT* __restrict__ K,
    ushortT* __restrict__ V)
{
    __shared__ float wq[32 * 68];
    __shared__ float wk[32 * 68];
    __shared__ float wv[32 * 68];
    __shared__ float xs[16 * 68];

    const int tid  = threadIdx.x;
    const int ns   = blockIdx.x >> 1;
    const int half = blockIdx.x & 1;

    {
        const int h  = tid >> 4;
        const int d0 = (tid & 15) * 4;
        const float4 a = ((const float4*)(x + (size_t)ns * EMB))[tid];
        *(float4*)&xs[h * 68 + d0] = a;
    }
#pragma unroll
    for (int j = 0; j < 2; ++j) {
        const int f4 = j * 256 + tid;
        const int e  = f4 >> 4;
        const int d4 = f4 & 15;
        const int g  = half * 512 + f4;
        float4 a = ((const float4*)Wq)[g];
        a.x *= kQSCALE; a.y *= kQSCALE; a.z *= kQSCALE; a.w *= kQSCALE;
        *(float4*)&wq[e * 68 + d4 * 4] = a;
        *(float4*)&wk[e * 68 + d4 * 4] = ((const float4*)Wk)[g];
        *(float4*)&wv[e * 68 + d4 * 4] = ((const float4*)Wv)[g];
    }
    __syncthreads();

    const int el = tid >> 3;
    const int h0 = (tid & 7) * 2;

    float aq[2] = {0.f, 0.f}, ak[2] = {0.f, 0.f}, av[2] = {0.f, 0.f};

#pragma unroll
    for (int d4 = 0; d4 < 16; ++d4) {
        const float4 wqv = *(const float4*)&wq[el * 68 + d4 * 4];
        const float4 wkv = *(const float4*)&wk[el * 68 + d4 * 4];
        const float4 wvv = *(const float4*)&wv[el * 68 + d4 * 4];
#pragma unroll
        for (int hh = 0; hh < 2; ++hh) {
            const float4 xv = *(const float4*)&xs[(h0 + hh) * 68 + d4 * 4];
            aq[hh] = fmaf(xv.x, wqv.x, fmaf(xv.y, wqv.y, fmaf(xv.z, wqv.z, fmaf(xv.w, wqv.w, aq[hh]))));
            ak[hh] = fmaf(xv.x, wkv.x, fmaf(xv.y, wkv.y, fmaf(xv.z, wkv.z, fmaf(xv.w, wkv.w, ak[hh]))));
            av[hh] = fmaf(xv.x, wvv.x, fmaf(xv.y, wvv.y, fmaf(xv.z, wvv.z, fmaf(xv.w, wvv.w, av[hh]))));
        }
    }
    const size_t off = (size_t)ns * EMB + half * 512 + 2 * tid;   // even
    *(ushort2*)&Q[off] = make_ushort2(f2bf(aq[0]), f2bf(aq[1]));
    *(ushort2*)&K[off] = make_ushort2(f2bf(ak[0]), f2bf(ak[1]));
    *(ushort2*)&V[off] = make_ushort2(f2bf(av[0]), f2bf(av[1]));
}

// ---------------------------------------------------------------------------
// Kernel 2: fused energy -> softmax(h) -> sum(t). bf16 Q/K/V.
// Wave tile: 2 s-values x half e-range (eh). Lane l = one uint4 (8 bf16):
// e = 32*eh + (l>>1), h-octet 8*(l&1). h-sum = 7 local adds + 1 shfl_xor(1).
// Round-6 changes: q unpack hoisted; NO sched_barrier (streams interleave
// for ILP); explicit register double-buffer on K/V so iter t+1's loads are
// in flight during iter t's math (hides L2 latency inside one wave).
// Grid: 2n * 32st(8s) * 2eh * 16tc = 2048 blocks, 4 waves each.
// ---------------------------------------------------------------------------
__global__ __attribute__((amdgpu_waves_per_eu(4, 8))) __launch_bounds__(256)
void attn_kernel(
    const ushortT* __restrict__ Q,
    const ushortT* __restrict__ K,
    const ushortT* __restrict__ V,
    float* __restrict__ AO)
{
    const int b    = blockIdx.x;
    const int tc   = b & 15;
    const int eh   = (b >> 4) & 1;
    const int st   = (b >> 5) & 31;
    const int n    = b >> 10;
    const int wave = threadIdx.x >> 6;
    const int l    = threadIdx.x & 63;
    const int s0   = st * 8 + wave * 2;
    const int t0   = tc * 16;

    float qa0[8], qa1[8];
    {
        const uint4* qp = (const uint4*)(Q + (size_t)(n * SQL + s0) * EMB + 512 * eh) + l;
        unpk8(qp[0], qa0);
        unpk8(qp[128], qa1);   // next s row = 1024 ushorts = 128 uint4
    }

    float a0[8], a1[8];
#pragma unroll
    for (int i = 0; i < 8; ++i) { a0[i] = 0.f; a1[i] = 0.f; }

    const uint4* kp = (const uint4*)(K + (size_t)(n * SQL + t0) * EMB + 512 * eh) + l;
    const uint4* vp = (const uint4*)(V + (size_t)(n * SQL + t0) * EMB + 512 * eh) + l;

    uint4 kk = kp[0];
    uint4 vv = vp[0];
    kp += 128; vp += 128;

    for (int tt = 0; tt < 16; ++tt) {
        uint4 kn, vn;
        if (tt < 15) {                // prefetch next t (reg double-buffer)
            kn = kp[0];
            vn = vp[0];
            kp += 128; vp += 128;
        }
        float ku[8], vu[8], p0[8], p1[8];
        unpk8(kk, ku);
#pragma unroll
        for (int i = 0; i < 8; ++i) p0[i] = fexp2(qa0[i] * ku[i]);
#pragma unroll
        for (int i = 0; i < 8; ++i) p1[i] = fexp2(qa1[i] * ku[i]);
        float u0 = ((p0[0] + p0[1]) + (p0[2] + p0[3])) + ((p0[4] + p0[5]) + (p0[6] + p0[7]));
        float u1 = ((p1[0] + p1[1]) + (p1[2] + p1[3])) + ((p1[4] + p1[5]) + (p1[6] + p1[7]));
        u0 += __shfl_xor(u0, 1);
        u1 += __shfl_xor(u1, 1);
        const float rs0 = frcp(u0);
        const float rs1 = frcp(u1);
        unpk8(vv, vu);
#pragma unroll
        for (int i = 0; i < 8; ++i) {
            a0[i] = fmaf(p0[i] * rs0, vu[i], a0[i]);
            a1[i] = fmaf(p1[i] * rs1, vu[i], a1[i]);
        }
        kk = kn; vv = vn;
    }

    // element (within row) = 512eh + 8l + c  ->  e = 32eh+(l>>1), h = 8(l&1)+c
    // AO channel = h*64 + e = 512(l&1) + 64c + 32eh + (l>>1)
    float* base0 = AO + (size_t)(n * SQL + s0) * EMB + 512 * (l & 1) + 32 * eh + (l >> 1);
    float* base1 = base0 + EMB;
#pragma unroll
    for (int c = 0; c < 8; ++c) {
        atomicAdd(base0 + 64 * c, a0[c]);
        atomicAdd(base1 + 64 * c, a1[c]);
    }
}

// ---------------------------------------------------------------------------
// Kernel 3: out = AO @ Wo^T (f32 vector GEMM). 64r x 32j tile, k-split 4.
// Grid = 8rt * 32jt * 4kc = 1024 blocks. Deterministic partials P[kc].
// ---------------------------------------------------------------------------
__global__ __launch_bounds__(256) void proj_kernel(
    const float* __restrict__ A,
    const float* __restrict__ Wo,
    float* __restrict__ P)
{
    __shared__ float As[32][68];
    __shared__ float Ws[32][36];

    const int b  = blockIdx.x;
    const int kc = b & 3;
    const int jt = (b >> 2) & 31;
    const int rt = b >> 7;
    const int tid = threadIdx.x;
    const int tx = tid & 15;
    const int ty = tid >> 4;
    const int r0 = rt * 64, j0 = jt * 32, k0 = kc * 256;

    float2 c2[4];
#pragma unroll
    for (int i = 0; i < 4; ++i) c2[i] = make_float2(0.f, 0.f);

    for (int kt = 0; kt < 8; ++kt) {
        const int kb = k0 + kt * 32;
        __syncthreads();
#pragma unroll
        for (int it = 0; it < 2; ++it) {
            const int f   = it * 256 + tid;
            const int row = f >> 3;
            const int kq  = f & 7;
            const float4 a = *(const float4*)&A[(size_t)(r0 + row) * EMB + kb + kq * 4];
            As[kq * 4 + 0][row] = a.x;
            As[kq * 4 + 1][row] = a.y;
            As[kq * 4 + 2][row] = a.z;
            As[kq * 4 + 3][row] = a.w;
        }
        {
            const int row = tid >> 3;
            const int kq  = tid & 7;
            const float4 w = *(const float4*)&Wo[(size_t)(j0 + row) * EMB + kb + kq * 4];
            Ws[kq * 4 + 0][row] = w.x;
            Ws[kq * 4 + 1][row] = w.y;
            Ws[kq * 4 + 2][row] = w.z;
            Ws[kq * 4 + 3][row] = w.w;
        }
        __syncthreads();
#pragma unroll
        for (int kk = 0; kk < 32; ++kk) {
            const float4 a4 = *(const float4*)&As[kk][ty * 4];
            const float2 w2 = *(const float2*)&Ws[kk][tx * 2];
            c2[0].x = fmaf(a4.x, w2.x, c2[0].x); c2[0].y = fmaf(a4.x, w2.y, c2[0].y);
            c2[1].x = fmaf(a4.y, w2.x, c2[1].x); c2[1].y = fmaf(a4.y, w2.y, c2[1].y);
            c2[2].x = fmaf(a4.z, w2.x, c2[2].x); c2[2].y = fmaf(a4.z, w2.y, c2[2].y);
            c2[3].x = fmaf(a4.w, w2.x, c2[3].x); c2[3].y = fmaf(a4.w, w2.y, c2[3].y);
        }
    }

    float* p = P + (size_t)kc * 524288;
#pragma unroll
    for (int rr = 0; rr < 4; ++rr) {
        *(float2*)&p[(size_t)(r0 + ty * 4 + rr) * EMB + j0 + tx * 2] = c2[rr];
    }
}

__global__ __launch_bounds__(256) void reduce_kernel(
    const float* __restrict__ P,
    const float* __restrict__ bo,
    float* __restrict__ out)
{
    const int f4 = blockIdx.x * 256 + threadIdx.x;   // 131072 float4s
    const float4* P4 = (const float4*)P;
    const float4 a = P4[f4];
    const float4 b = P4[131072 + f4];
    const float4 c = P4[262144 + f4];
    const float4 d = P4[393216 + f4];
    const float4 bb = ((const float4*)bo)[f4 & 255];
    float4 o;
    o.x = ((a.x + b.x) + (c.x + d.x)) + bb.x;
    o.y = ((a.y + b.y) + (c.y + d.y)) + bb.y;
    o.z = ((a.z + b.z) + (c.z + d.z)) + bb.z;
    o.w = ((a.w + b.w) + (c.w + d.w)) + bb.w;
    ((float4*)out)[f4] = o;
}

extern "C" void kernel_launch(void* const* d_in, const int* in_sizes, int n_in,
                              void* d_out, int out_size, void* d_ws, size_t ws_size,
                              hipStream_t stream)
{
    const float* x  = (const float*)d_in[0];
    const float* Wq = (const float*)d_in[1];
    const float* Wk = (const float*)d_in[2];
    const float* Wv = (const float*)d_in[3];
    const float* Wo = (const float*)d_in[4];
    const float* bo = (const float*)d_in[5];

    float* ws = (float*)d_ws;
    ushortT* Q = (ushortT*)ws;              // 524288 bf16 = 1 MB
    ushortT* K = (ushortT*)(ws + 262144);   // 1 MB
    ushortT* V = (ushortT*)(ws + 524288);   // 1 MB
    float* AO  = ws + 786432;               // 524288 f32 = 2 MB
    float* P   = ws + 1310720;              // 4 x 524288 f32 = 8 MB

    hipMemsetAsync(AO, 0, 524288 * sizeof(float), stream);
    qkv_kernel<<<1024, 256, 0, stream>>>(x, Wq, Wk, Wv, Q, K, V);
    attn_kernel<<<2048, 256, 0, stream>>>(Q, K, V, AO);
    proj_kernel<<<1024, 256, 0, stream>>>(AO, Wo, P);
    reduce_kernel<<<512, 256, 0, stream>>>(P, bo, (float*)d_out);
}